// Round 1
// baseline (177.534 us; speedup 1.0000x reference)
//
#include <hip/hip_runtime.h>
#include <hip/hip_bf16.h>
#include <stdint.h>

typedef __attribute__((ext_vector_type(8))) short short8;
typedef __attribute__((ext_vector_type(4))) float f32x4;

// ---------------- ws layout (bytes) ----------------
// Xpad granules: [b(8)][cb(8)][y(66)][x(66)][gslot(4)] * 16B = 17,842,176
#define XP_BYTES   17842176
#define XP_PAD     1024
#define OFF_W9     (XP_BYTES + XP_PAD)            // 17,843,200
#define W9_BYTES   (8*9*256*32*2)                 // 1,179,648
#define OFF_WFULL  (OFF_W9 + W9_BYTES)            // 19,022,848
#define WFULL_BYTES (256*256*16*4)                // 4,194,304
#define OFF_BIAS   (OFF_WFULL + WFULL_BYTES)      // 23,217,152
#define OFF_H2     (OFF_BIAS + 1024)              // 23,218,176

__device__ __forceinline__ short f2bf(float f) {
  __hip_bfloat16 h = __float2bfloat16(f);
  return *reinterpret_cast<short*>(&h);
}

__device__ __forceinline__ void gl_lds16(const void* g, void* l) {
  __builtin_amdgcn_global_load_lds(
      (const __attribute__((address_space(1))) void*)g,
      (__attribute__((address_space(3))) void*)l, 16, 0, 0);
}

// H2[c2,d,u,j,k] = sum_v G2[c2,v,u,j] * G3[d,v,k]
__global__ void k_h2(const float* __restrict__ core2,
                     const float* __restrict__ core3,
                     float* __restrict__ H2) {
  int idx = blockIdx.x * 256 + threadIdx.x;        // 65536
  int k = idx & 7, j = (idx >> 3) & 7, u = (idx >> 6) & 15;
  int d = (idx >> 10) & 7, c2 = (idx >> 13) & 7;
  float s = 0.f;
  for (int v = 0; v < 16; ++v)
    s += core2[(c2 * 16 + v) * 128 + u * 8 + j] * core3[d * 128 + v * 8 + k];
  H2[idx] = s;
}

// Wfull[o,c,r] = sum_u G1[a,u,r,i] * H2[c2,d,u,j,k]
__global__ void k_wfull(const float* __restrict__ core1,
                        const float* __restrict__ H2,
                        float* __restrict__ Wfull) {
  int o = blockIdx.x, c = threadIdx.x;
  int a = o >> 6, c2 = (o >> 3) & 7, d = o & 7;
  int i = c >> 6, j = (c >> 3) & 7, k = c & 7;
  float Wr[16];
#pragma unroll
  for (int r = 0; r < 16; ++r) Wr[r] = 0.f;
  for (int u = 0; u < 16; ++u) {
    float h = H2[(((c2 * 8 + d) * 16 + u) * 8 + j) * 8 + k];
    const float* c1 = core1 + (a * 16 + u) * 64 + i;
#pragma unroll
    for (int r = 0; r < 16; ++r) Wr[r] += c1[r * 4] * h;
  }
  float* wp = Wfull + ((size_t)o * 256 + c) * 16;
#pragma unroll
  for (int r = 0; r < 16; ++r) wp[r] = Wr[r];
}

// K9 bf16, swizzled layout: [cb][t][o(256)][gslot(4)][8]
__global__ void k_w9(const float* __restrict__ Wfull,
                     const float* __restrict__ convw,
                     short* __restrict__ W9) {
  int c = blockIdx.x, o = threadIdx.x;
  const float* wp = Wfull + ((size_t)o * 256 + c) * 16;
  float Wr[16];
#pragma unroll
  for (int r = 0; r < 16; ++r) Wr[r] = wp[r];
  int cb = c >> 5, cl = c & 31, g = cl >> 3, pos = cl & 7;
  int gslot = g ^ (o & 3);
#pragma unroll
  for (int t = 0; t < 9; ++t) {
    float s = 0.f;
#pragma unroll
    for (int r = 0; r < 16; ++r) s += Wr[r] * convw[r * 9 + t];
    W9[((size_t)((cb * 9 + t) * 256 + o)) * 32 + gslot * 8 + pos] = f2bf(s);
  }
}

// bias[o] = sum_{c,r} Wfull[o,c,r] * conv_b[r]
__global__ void k_bias(const float* __restrict__ Wfull,
                       const float* __restrict__ convb,
                       float* __restrict__ bias) {
  __shared__ float red[256];
  int o = blockIdx.x, c = threadIdx.x;
  const float* wp = Wfull + ((size_t)o * 256 + c) * 16;
  float s = 0.f;
#pragma unroll
  for (int r = 0; r < 16; ++r) s += wp[r] * convb[r];
  red[c] = s;
  __syncthreads();
  for (int st = 128; st > 0; st >>= 1) {
    if (c < st) red[c] += red[c + st];
    __syncthreads();
  }
  if (c == 0) bias[o] = red[0];
}

// pad+transpose: X (B,256,64,64) fp32 -> Xpad bf16 granules (interior only)
__global__ void k_pad(const float* __restrict__ X, short* __restrict__ Xp) {
  int ys = blockIdx.x, b = blockIdx.y;
  int t = threadIdx.x;
  int x = t & 63, ci = t >> 6;
  int y = ys + 1, xp = x + 1;
  for (int i = 0; i < 64; ++i) {
    int c = ci * 64 + i;
    float v = X[((size_t)(b * 256 + c) * 64 + ys) * 64 + x];
    int cb = c >> 5, cl = c & 31;
    int gslot = (cl >> 3) ^ (xp & 3);
    size_t dst = ((size_t)((((b * 8 + cb) * 66 + y) * 66 + xp) * 4 + gslot)) * 8 + (cl & 7);
    Xp[dst] = f2bf(v);
  }
}

// main GEMM: out[b,o,h,w] = bias[o] + sum_{c,t} K9[o,c,t]*Xpad[b,c,h+dy,w+dx]
__global__ __launch_bounds__(256, 2) void k_gemm(
    const short* __restrict__ Xp, const short* __restrict__ W9,
    const float* __restrict__ bias, float* __restrict__ out) {
  __shared__ __align__(16) short XL[12800];   // 1600 granules (1584 used), 25,600 B
  __shared__ __align__(16) short WL[18432];   // [t(9)][o(64)][c(32)], 36,864 B

  const int tid  = threadIdx.x;
  const int lane = tid & 63;
  const int wv   = tid >> 6;           // 4 waves; wave = output row within tile
  const int l15  = lane & 15;
  const int gl   = lane >> 4;          // k-granule 0..3
  const int h0    = blockIdx.x << 2;   // 4 output rows / block
  const int oBase = blockIdx.y << 6;   // 64 out-channels / block
  const int b     = blockIdx.z;

  f32x4 acc[4][4];
#pragma unroll
  for (int io = 0; io < 4; ++io)
#pragma unroll
    for (int ip = 0; ip < 4; ++ip)
      acc[io][ip] = (f32x4){0.f, 0.f, 0.f, 0.f};

  for (int cb = 0; cb < 8; ++cb) {
    __syncthreads();
    // stage weights: 36 wave-chunks of 1 KB, contiguous both sides
#pragma unroll 1
    for (int q = wv; q < 36; q += 4) {
      const int t = q >> 2, sub = q & 3;
      const short* g = W9 +
          (((size_t)(((cb * 9 + t) << 8) + oBase + (sub << 4))) << 5) + (lane << 3);
      gl_lds16(g, &WL[((t << 6) + (sub << 4)) << 5]);
    }
    // stage X: 25 wave-chunks (last partially dummy; global padded)
    const size_t xb = ((size_t)(((b << 3) + cb) * 66 + h0) * 66) << 5;
#pragma unroll 1
    for (int q = wv; q < 25; q += 4) {
      gl_lds16(Xp + xb + (q << 9) + (lane << 3), &XL[q << 9]);
    }
    __syncthreads();
#pragma unroll
    for (int t = 0; t < 9; ++t) {
      const int dy = t / 3, dx = t % 3;
      const int row = wv + dy;
      short8 af[4], bfr[4];
#pragma unroll
      for (int io = 0; io < 4; ++io) {
        const int ol = (io << 4) + l15;
        af[io] = *(const short8*)&WL[(((t << 6) + ol) << 5) + ((gl ^ (ol & 3)) << 3)];
      }
#pragma unroll
      for (int ip = 0; ip < 4; ++ip) {
        const int x = (ip << 4) + l15 + dx;
        bfr[ip] = *(const short8*)&XL[(((row * 66 + x) << 2) + (gl ^ (x & 3))) << 3];
      }
#pragma unroll
      for (int io = 0; io < 4; ++io)
#pragma unroll
        for (int ip = 0; ip < 4; ++ip)
          acc[io][ip] = __builtin_amdgcn_mfma_f32_16x16x32_bf16(
              af[io], bfr[ip], acc[io][ip], 0, 0, 0);
    }
  }

  const int h = h0 + wv;
#pragma unroll
  for (int io = 0; io < 4; ++io) {
#pragma unroll
    for (int r = 0; r < 4; ++r) {
      const int oG = oBase + (io << 4) + (gl << 2) + r;
      const float bv = bias[oG];
      float* op = out + (((size_t)((b << 8) + oG)) << 12) + (h << 6);
#pragma unroll
      for (int ip = 0; ip < 4; ++ip)
        op[(ip << 4) + l15] = acc[io][ip][r] + bv;
    }
  }
}

extern "C" void kernel_launch(void* const* d_in, const int* in_sizes, int n_in,
                              void* d_out, int out_size, void* d_ws, size_t ws_size,
                              hipStream_t stream) {
  (void)in_sizes; (void)n_in; (void)out_size; (void)ws_size;
  const float* X     = (const float*)d_in[0];
  const float* convw = (const float*)d_in[1];
  const float* convb = (const float*)d_in[2];
  const float* core1 = (const float*)d_in[3];
  const float* core2 = (const float*)d_in[4];
  const float* core3 = (const float*)d_in[5];
  float* out = (float*)d_out;
  char*  ws  = (char*)d_ws;

  short* Xp    = (short*)ws;
  short* W9    = (short*)(ws + OFF_W9);
  float* Wfull = (float*)(ws + OFF_WFULL);
  float* bias  = (float*)(ws + OFF_BIAS);
  float* H2    = (float*)(ws + OFF_H2);

  // zero Xpad (borders must be 0; ws is poisoned each call)
  hipMemsetAsync(Xp, 0, XP_BYTES + XP_PAD, stream);
  k_pad  <<<dim3(64, 8), 256, 0, stream>>>(X, Xp);
  k_h2   <<<256, 256, 0, stream>>>(core2, core3, H2);
  k_wfull<<<256, 256, 0, stream>>>(core1, H2, Wfull);
  k_w9   <<<256, 256, 0, stream>>>(Wfull, convw, W9);
  k_bias <<<256, 256, 0, stream>>>(Wfull, convb, bias);
  k_gemm <<<dim3(16, 4, 8), 256, 0, stream>>>(Xp, W9, bias, out);
}

// Round 2
// 138.421 us; speedup vs baseline: 1.2826x; 1.2826x over previous
//
#include <hip/hip_runtime.h>
#include <hip/hip_bf16.h>
#include <stdint.h>

typedef __attribute__((ext_vector_type(8))) short short8;
typedef __attribute__((ext_vector_type(4))) float f32x4;

// ---------------- ws layout (bytes) ----------------
// Xpad granules: [b(8)][cb(8)][y(66)][x(66)][gslot(4)] * 16B = 17,842,176
#define XP_BYTES   17842176
#define XP_PAD     1024
#define OFF_W9     (XP_BYTES + XP_PAD)            // 17,843,200
#define W9_BYTES   (8*9*256*32*2)                 // 1,179,648
#define OFF_BIAS   (OFF_W9 + W9_BYTES)

__device__ __forceinline__ short f2bf(float f) {
  __hip_bfloat16 h = __float2bfloat16(f);
  return *reinterpret_cast<short*>(&h);
}

__device__ __forceinline__ void gl_lds16(const void* g, void* l) {
  __builtin_amdgcn_global_load_lds(
      (const __attribute__((address_space(1))) void*)g,
      (__attribute__((address_space(3))) void*)l, 16, 0, 0);
}

// Fused weight prep: H2 slice in LDS -> Wfull rows in regs -> W9 taps + bias.
// One block per o (256 blocks), one thread per c (256 threads).
__global__ void k_weights(const float* __restrict__ core1,
                          const float* __restrict__ core2,
                          const float* __restrict__ core3,
                          const float* __restrict__ convw,
                          const float* __restrict__ convb,
                          short* __restrict__ W9, float* __restrict__ bias) {
  __shared__ float H2s[1024];   // [u(16)][j(8)][k(8)]
  __shared__ float red[256];
  const int o = blockIdx.x, c = threadIdx.x;
  const int a = o >> 6, c2 = (o >> 3) & 7, d = o & 7;
  // phase 1: H2[c2,d,u,j,k] = sum_v G2[c2,v,u,j]*G3[d,v,k]
#pragma unroll
  for (int p = 0; p < 4; ++p) {
    int idx = c + (p << 8);
    int k = idx & 7, j = (idx >> 3) & 7, u = idx >> 6;
    float s = 0.f;
#pragma unroll
    for (int v = 0; v < 16; ++v)
      s += core2[(c2 * 16 + v) * 128 + u * 8 + j] * core3[d * 128 + v * 8 + k];
    H2s[idx] = s;
  }
  __syncthreads();
  // phase 2: Wr[r] = Wfull[o,c,r] = sum_u G1[a,u,r,i]*H2s[u,j,k]
  const int i = c >> 6, j = (c >> 3) & 7, k = c & 7;
  float Wr[16];
#pragma unroll
  for (int r = 0; r < 16; ++r) Wr[r] = 0.f;
  for (int u = 0; u < 16; ++u) {
    float h = H2s[u * 64 + j * 8 + k];
    const float* c1 = core1 + (a * 16 + u) * 64 + i;
#pragma unroll
    for (int r = 0; r < 16; ++r) Wr[r] += c1[r * 4] * h;
  }
  // phase 3a: 9 conv taps, swizzled W9 layout [cb][t][o][gslot][8]
  const int cb = c >> 5, cl = c & 31, g = cl >> 3, pos = cl & 7;
  const int gslot = g ^ (o & 3);
#pragma unroll
  for (int t = 0; t < 9; ++t) {
    float s = 0.f;
#pragma unroll
    for (int r = 0; r < 16; ++r) s += Wr[r] * convw[r * 9 + t];
    W9[((size_t)((cb * 9 + t) * 256 + o)) * 32 + gslot * 8 + pos] = f2bf(s);
  }
  // phase 3b: bias[o] = sum_{c,r} Wfull[o,c,r]*convb[r]
  float s = 0.f;
#pragma unroll
  for (int r = 0; r < 16; ++r) s += Wr[r] * convb[r];
  red[c] = s;
  __syncthreads();
  for (int st = 128; st > 0; st >>= 1) {
    if (c < st) red[c] += red[c + st];
    __syncthreads();
  }
  if (c == 0) bias[o] = red[0];
}

// pad+transpose: X (B,256,64,64) fp32 -> Xpad bf16 granules (interior only).
// Each thread packs one full 16-B granule (8 consecutive channels) and emits
// one dwordx4 store. Reads are wave-contiguous 256 B per k-step.
__global__ void k_pad(const float* __restrict__ X, short* __restrict__ Xp) {
  const int y = blockIdx.x, b = blockIdx.y, cb = blockIdx.z;
  const int t = threadIdx.x;
  const int x = t & 63, sub = t >> 6;       // sub = channel-group g (0..3)
  const int xp = x + 1, yp = y + 1;
  const int gslot = sub ^ (xp & 3);
  const float* src = X + ((size_t)(b * 256 + cb * 32 + sub * 8) * 64 + y) * 64 + x;
  short8 v;
#pragma unroll
  for (int k = 0; k < 8; ++k) v[k] = f2bf(src[(size_t)k * 4096]);
  const size_t granule = ((size_t)((b * 8 + cb) * 66 + yp) * 66 + xp) * 4 + gslot;
  *(short8*)(Xp + granule * 8) = v;
}

// main GEMM: out[b,o,h,w] = bias[o] + sum_{c,t} K9[o,c,t]*Xpad[b,c,h+dy,w+dx]
__global__ __launch_bounds__(256, 2) void k_gemm(
    const short* __restrict__ Xp, const short* __restrict__ W9,
    const float* __restrict__ bias, float* __restrict__ out) {
  __shared__ __align__(16) short XL[12800];   // 1600 granules (1584 used)
  __shared__ __align__(16) short WL[18432];   // [t(9)][o(64)][c(32)]

  const int tid  = threadIdx.x;
  const int lane = tid & 63;
  const int wv   = tid >> 6;           // 4 waves; wave = output row within tile
  const int l15  = lane & 15;
  const int gl   = lane >> 4;          // k-granule 0..3
  const int h0    = blockIdx.x << 2;   // 4 output rows / block
  const int oBase = blockIdx.y << 6;   // 64 out-channels / block
  const int b     = blockIdx.z;

  f32x4 acc[4][4];
#pragma unroll
  for (int io = 0; io < 4; ++io)
#pragma unroll
    for (int ip = 0; ip < 4; ++ip)
      acc[io][ip] = (f32x4){0.f, 0.f, 0.f, 0.f};

  for (int cb = 0; cb < 8; ++cb) {
    __syncthreads();
    // stage weights: 36 wave-chunks of 1 KB, contiguous both sides
#pragma unroll 1
    for (int q = wv; q < 36; q += 4) {
      const int t = q >> 2, sub = q & 3;
      const short* g = W9 +
          (((size_t)(((cb * 9 + t) << 8) + oBase + (sub << 4))) << 5) + (lane << 3);
      gl_lds16(g, &WL[((t << 6) + (sub << 4)) << 5]);
    }
    // stage X: 25 wave-chunks (last partially dummy; global padded)
    const size_t xb = ((size_t)(((b << 3) + cb) * 66 + h0) * 66) << 5;
#pragma unroll 1
    for (int q = wv; q < 25; q += 4) {
      gl_lds16(Xp + xb + (q << 9) + (lane << 3), &XL[q << 9]);
    }
    __syncthreads();
#pragma unroll
    for (int t = 0; t < 9; ++t) {
      const int dy = t / 3, dx = t % 3;
      const int row = wv + dy;
      short8 af[4], bfr[4];
#pragma unroll
      for (int io = 0; io < 4; ++io) {
        const int ol = (io << 4) + l15;
        af[io] = *(const short8*)&WL[(((t << 6) + ol) << 5) + ((gl ^ (ol & 3)) << 3)];
      }
#pragma unroll
      for (int ip = 0; ip < 4; ++ip) {
        const int x = (ip << 4) + l15 + dx;
        bfr[ip] = *(const short8*)&XL[(((row * 66 + x) << 2) + (gl ^ (x & 3))) << 3];
      }
#pragma unroll
      for (int io = 0; io < 4; ++io)
#pragma unroll
        for (int ip = 0; ip < 4; ++ip)
          acc[io][ip] = __builtin_amdgcn_mfma_f32_16x16x32_bf16(
              af[io], bfr[ip], acc[io][ip], 0, 0, 0);
    }
  }

  const int h = h0 + wv;
#pragma unroll
  for (int io = 0; io < 4; ++io) {
#pragma unroll
    for (int r = 0; r < 4; ++r) {
      const int oG = oBase + (io << 4) + (gl << 2) + r;
      const float bv = bias[oG];
      float* op = out + (((size_t)((b << 8) + oG)) << 12) + (h << 6);
#pragma unroll
      for (int ip = 0; ip < 4; ++ip)
        op[(ip << 4) + l15] = acc[io][ip][r] + bv;
    }
  }
}

extern "C" void kernel_launch(void* const* d_in, const int* in_sizes, int n_in,
                              void* d_out, int out_size, void* d_ws, size_t ws_size,
                              hipStream_t stream) {
  (void)in_sizes; (void)n_in; (void)out_size; (void)ws_size;
  const float* X     = (const float*)d_in[0];
  const float* convw = (const float*)d_in[1];
  const float* convb = (const float*)d_in[2];
  const float* core1 = (const float*)d_in[3];
  const float* core2 = (const float*)d_in[4];
  const float* core3 = (const float*)d_in[5];
  float* out = (float*)d_out;
  char*  ws  = (char*)d_ws;

  short* Xp   = (short*)ws;
  short* W9   = (short*)(ws + OFF_W9);
  float* bias = (float*)(ws + OFF_BIAS);

  // zero Xpad (borders must be 0; ws is poisoned each call)
  hipMemsetAsync(Xp, 0, XP_BYTES + XP_PAD, stream);
  k_weights<<<256, 256, 0, stream>>>(core1, core2, core3, convw, convb, W9, bias);
  k_pad    <<<dim3(64, 8, 8), 256, 0, stream>>>(X, Xp);
  k_gemm   <<<dim3(16, 4, 8), 256, 0, stream>>>(Xp, W9, bias, out);
}